// Round 3
// baseline (113.114 us; speedup 1.0000x reference)
//
#include <hip/hip_runtime.h>

// HyperLayer: y[b, f0/c0] += v * w0 * (wf1*x[b,f1] + wc1*x[b,c1])
// B=16, N=262144, DIM=8192.
//
// R18: R17 post-mortem — fused global-atomic flush (4.2M device-scope fp32
// atomics) cost ~+4us vs R15's L2-resident partials round-trip: on 8-XCD
// gfx950 those atomics execute at the IF coherence point, not local L2.
// Revert to partials-in-ws, but fuse the reduction via the split-K
// "last block" pattern:
//  - scatter block stores its partial row (plain float4 stores),
//  - bumps cnt[b] with __hip_atomic_fetch_add(ACQ_REL, AGENT) — release
//    writes back this XCD's L2, acquire invalidates (per-XCD L2s are NOT
//    coherent; kernel-boundary coherence no longer protects us once fused),
//  - the block seeing old==SPLITS-1 sums 16 rows, plain-stores y.
//  => 16 coherence-point atomics total; reduce tail overlaps other batches'
//     scatter tails; one launch node replaced by a trivial counter-zero
//     kernel (must be a KERNEL: ws is re-poisoned by the harness fills each
//     replay, and memset nodes don't survive capture — R16 lesson).
//  - point loads vectorized: float4 ri (2 pts) + float2 rv per lane-iter.
//  - __launch_bounds__(1024,4): grid is 1 block/CU (LDS 64KB), the old ,8
//    only capped VGPRs at 64 for no occupancy gain.

#define BATCH 16
#define NPTS 262144
#define DIM 8192
#define SPLITS 16
#define PTS_PER_BLOCK (NPTS / SPLITS)     // 16384
#define BLOCK 1024
#define PAIRS_PER_BLOCK (PTS_PER_BLOCK/2) // 8192
#define PITERS (PAIRS_PER_BLOCK / BLOCK)  // 8 -> fully unrolled

#define FP_SCALE 4194304.0f               // 2^22
#define FP_INV   (1.0f / 4194304.0f)

// Zero the per-batch completion counters (ws is poisoned every replay).
__global__ __launch_bounds__(64) void zero_cnt_kernel(unsigned int* __restrict__ cnt)
{
    if (threadIdx.x < BATCH) cnt[threadIdx.x] = 0u;
}

__global__ __launch_bounds__(BLOCK, 4) void hyper_scatter_lastblock_kernel(
    const float* __restrict__ x,        // [B, DIM]
    const float* __restrict__ ri,       // [B, N, 2]
    const float* __restrict__ rv,       // [B, N]
    float* __restrict__ partials,       // [B*SPLITS, DIM] in ws
    unsigned int* __restrict__ cnt,     // [B] in ws, pre-zeroed
    float* __restrict__ y)              // [B, DIM]
{
    __shared__ float        x_s[DIM];   // 32 KB staged x row (LDS gather)
    __shared__ unsigned int S_s[DIM];   // 32 KB fixed-point accumulators
    __shared__ unsigned int last_flag;

    const int tid   = threadIdx.x;
    const int split = blockIdx.x;
    const int b     = blockIdx.y;

    const float4* x4 = (const float4*)(x + (size_t)b * DIM);
    float4* xs4 = (float4*)x_s;
    uint4*  ss4 = (uint4*)S_s;
    #pragma unroll
    for (int i = tid; i < DIM / 4; i += BLOCK) {
        xs4[i] = x4[i];                     // L2-hit after first split per b
        ss4[i] = make_uint4(0u, 0u, 0u, 0u);
    }
    __syncthreads();

    const size_t base = (size_t)b * NPTS + (size_t)split * PTS_PER_BLOCK;
    const float4* ri4 = (const float4*)ri + (base >> 1);  // 2 points / float4
    const float2* rv2 = (const float2*)(rv + base);

    #pragma unroll
    for (int k = 0; k < PITERS; ++k) {
        const int p = tid + k * BLOCK;
        float4 r = ri4[p];      // {x0,y0, x1,y1}
        float2 v = rv2[p];

        #pragma unroll
        for (int q = 0; q < 2; ++q) {
            float rx = q ? r.z : r.x;
            float ry = q ? r.w : r.y;
            float vv = q ? v.y : v.x;

            // frac-based corner weights. Reference: w = 1-|corner-real| for
            // floor and ceil independently; integral index -> floor==ceil,
            // both weights 1, double count on the same slot.
            float f0 = floorf(rx);
            float fr0 = rx - f0;
            float wf0 = 1.0f - fr0;
            bool  int0 = (fr0 == 0.0f);
            float wc0 = int0 ? 1.0f : fr0;
            int   i0f = (int)f0;
            int   i0c = i0f + (int0 ? 0 : 1);

            float f1 = floorf(ry);
            float fr1 = ry - f1;
            float wf1 = 1.0f - fr1;
            bool  int1 = (fr1 == 0.0f);
            float wc1 = int1 ? 1.0f : fr1;
            int   i1f = (int)f1;
            int   i1c = i1f + (int1 ? 0 : 1);

            float xa = x_s[i1f];            // scattered LDS gather, near-free
            float xb = x_s[i1c];

            float vg = vv * (wf1 * xa + wc1 * xb);
            // Fixed-point integer LDS atomics (full-rate, order-independent).
            int ia = __float2int_rn(wf0 * vg * FP_SCALE);
            int ib = __float2int_rn(wc0 * vg * FP_SCALE);
            atomicAdd(&S_s[i0f], (unsigned int)ia);
            atomicAdd(&S_s[i0c], (unsigned int)ib);
        }
    }
    __syncthreads();

    // Decode fixed-point -> fp32, store partial row (coalesced).
    float* prow = partials + ((size_t)b * SPLITS + split) * DIM;
    #pragma unroll
    for (int i = tid; i < DIM; i += BLOCK) {
        prow[i] = (float)(int)S_s[i] * FP_INV;
    }

    // __syncthreads drains vmcnt (stores at L2); tid0's release fence +
    // agent-scope atomic write back this XCD's L2 before the count bump.
    __syncthreads();
    if (tid == 0) {
        __threadfence();   // agent release: L2 writeback
        unsigned int old = __hip_atomic_fetch_add(
            cnt + b, 1u, __ATOMIC_ACQ_REL, __HIP_MEMORY_SCOPE_AGENT);
        last_flag = (old == SPLITS - 1u) ? 1u : 0u;
        if (last_flag) __threadfence();  // acquire: invalidate L1/L2
    }
    __syncthreads();

    if (last_flag) {
        // All 16 partial rows for b are visible (each writer released its
        // L2 before bumping; we invalidated ours). Sum + plain store to y.
        const float4* p0 = (const float4*)(partials + (size_t)b * SPLITS * DIM);
        float4* yrow4 = (float4*)(y + (size_t)b * DIM);
        #pragma unroll
        for (int i = tid; i < DIM / 4; i += BLOCK) {     // 2 iters
            float4 acc = make_float4(0.f, 0.f, 0.f, 0.f);
            #pragma unroll
            for (int s = 0; s < SPLITS; ++s) {
                float4 t = p0[(size_t)s * (DIM / 4) + i];
                acc.x += t.x; acc.y += t.y; acc.z += t.z; acc.w += t.w;
            }
            yrow4[i] = acc;
        }
    }
}

// ---- Fallback path (ws too small): R17 fused-atomic version (correct). ----
__global__ __launch_bounds__(256) void zero_y_kernel(float* __restrict__ y)
{
    const int i = blockIdx.x * 256 + threadIdx.x;
    ((float4*)y)[i] = make_float4(0.f, 0.f, 0.f, 0.f);
}

__global__ __launch_bounds__(BLOCK, 4) void hyper_scatter_atomic_kernel(
    const float* __restrict__ x, const float* __restrict__ ri,
    const float* __restrict__ rv, float* __restrict__ y)
{
    __shared__ float        x_s[DIM];
    __shared__ unsigned int S_s[DIM];
    const int tid = threadIdx.x, split = blockIdx.x, b = blockIdx.y;
    const float4* x4 = (const float4*)(x + (size_t)b * DIM);
    float4* xs4 = (float4*)x_s;
    uint4*  ss4 = (uint4*)S_s;
    for (int i = tid; i < DIM / 4; i += BLOCK) {
        xs4[i] = x4[i];
        ss4[i] = make_uint4(0u, 0u, 0u, 0u);
    }
    __syncthreads();
    const size_t base = (size_t)b * NPTS + (size_t)split * PTS_PER_BLOCK;
    const float2* idx2 = (const float2*)ri + base;
    const float*  val  = rv + base;
    for (int i = tid; i < PTS_PER_BLOCK; i += BLOCK) {
        float2 r = idx2[i];
        float v  = val[i];
        float f0 = floorf(r.x), fr0 = r.x - f0;
        float wf0 = 1.0f - fr0;
        bool int0 = (fr0 == 0.0f);
        float wc0 = int0 ? 1.0f : fr0;
        int i0f = (int)f0, i0c = i0f + (int0 ? 0 : 1);
        float f1 = floorf(r.y), fr1 = r.y - f1;
        float wf1 = 1.0f - fr1;
        bool int1 = (fr1 == 0.0f);
        float wc1 = int1 ? 1.0f : fr1;
        int i1f = (int)f1, i1c = i1f + (int1 ? 0 : 1);
        float vg = v * (wf1 * x_s[i1f] + wc1 * x_s[i1c]);
        atomicAdd(&S_s[i0f], (unsigned int)__float2int_rn(wf0 * vg * FP_SCALE));
        atomicAdd(&S_s[i0c], (unsigned int)__float2int_rn(wc0 * vg * FP_SCALE));
    }
    __syncthreads();
    float* yrow = y + (size_t)b * DIM;
    for (int i = tid; i < DIM; i += BLOCK) {
        unsafeAtomicAdd(&yrow[i], (float)(int)S_s[i] * FP_INV);
    }
}

extern "C" void kernel_launch(void* const* d_in, const int* in_sizes, int n_in,
                              void* d_out, int out_size, void* d_ws, size_t ws_size,
                              hipStream_t stream) {
    const float* x  = (const float*)d_in[0];
    const float* ri = (const float*)d_in[1];
    const float* rv = (const float*)d_in[2];
    float* y = (float*)d_out;

    const size_t part_bytes = (size_t)BATCH * SPLITS * DIM * sizeof(float); // 8 MB
    const size_t need = part_bytes + BATCH * sizeof(unsigned int);

    if (ws_size >= need) {
        float* partials = (float*)d_ws;
        unsigned int* cnt = (unsigned int*)((char*)d_ws + part_bytes);
        zero_cnt_kernel<<<1, 64, 0, stream>>>(cnt);
        dim3 grid(SPLITS, BATCH);
        hyper_scatter_lastblock_kernel<<<grid, BLOCK, 0, stream>>>(
            x, ri, rv, partials, cnt, y);
    } else {
        zero_y_kernel<<<BATCH * DIM / 4 / 256, 256, 0, stream>>>(y);
        dim3 grid(SPLITS, BATCH);
        hyper_scatter_atomic_kernel<<<grid, BLOCK, 0, stream>>>(x, ri, rv, y);
    }
}

// Round 5
// 96.972 us; speedup vs baseline: 1.1665x; 1.1665x over previous
//
#include <hip/hip_runtime.h>

// HyperLayer: y[b, f0/c0] += v * w0 * (wf1*x[b,f1] + wc1*x[b,c1])
// B=16, N=262144, DIM=8192.
//
// R20 = R19 with the compile fix: __builtin_nontemporal_load rejects
// HIP_vector_type structs; use clang ext_vector_type floats instead.
// R19 rationale (unchanged, untested due to compile error):
//  - revert to measured-best R15 structure (98.8us: SPLITS=16, BLOCK=1024,
//    partials in ws + separate reduce kernel). Both fusion attempts lost
//    (R17 fused-atomic +3.4us, R18 last-block +14.3us): on 8-XCD gfx950,
//    kernel-boundary coherence beats in-kernel cross-XCD handshakes here.
//  - micro-opts only:
//  1. float4 ri (2 pts/load) + float2 rv — halves VMEM instrs in hot loop.
//  2. prefetch pair-iter 0 before the x-stage barrier — point loads don't
//     depend on LDS; overlaps their HBM latency with the x staging.
//  3. nontemporal loads on ri/rv (stream-once, 48MB) — less L2 pollution,
//     keeps the 8MB partials resident for the reduce kernel.
// Structural floor: ~85us harness ws-poison fills (untouchable) + 7.7us
// input read + ~2us partials + ~2us launches.

#define BATCH 16
#define NPTS 262144
#define DIM 8192
#define SPLITS 16
#define PTS_PER_BLOCK (NPTS / SPLITS)       // 16384
#define BLOCK 1024
#define PAIRS_PER_BLOCK (PTS_PER_BLOCK / 2) // 8192
#define PITERS (PAIRS_PER_BLOCK / BLOCK)    // 8 pair-iters per thread

#define FP_SCALE 4194304.0f                 // 2^22
#define FP_INV   (1.0f / 4194304.0f)

// clang-native vectors: __builtin_nontemporal_load accepts these (it
// rejects HIP_vector_type structs).
typedef float vf4 __attribute__((ext_vector_type(4)));
typedef float vf2 __attribute__((ext_vector_type(2)));

__device__ __forceinline__ void process_point(
    float rx, float ry, float vv,
    const float* __restrict__ x_s, unsigned int* __restrict__ S_s)
{
    // frac-based corner weights. Reference semantics: w = 1-|corner-real|
    // for floor and ceil independently; integral index -> floor==ceil,
    // both weights 1, both land on the same slot (double count).
    float f0 = floorf(rx);
    float fr0 = rx - f0;                 // in [0,1)
    float wf0 = 1.0f - fr0;
    bool  int0 = (fr0 == 0.0f);
    float wc0 = int0 ? 1.0f : fr0;
    int   i0f = (int)f0;
    int   i0c = i0f + (int0 ? 0 : 1);

    float f1 = floorf(ry);
    float fr1 = ry - f1;
    float wf1 = 1.0f - fr1;
    bool  int1 = (fr1 == 0.0f);
    float wc1 = int1 ? 1.0f : fr1;
    int   i1f = (int)f1;
    int   i1c = i1f + (int1 ? 0 : 1);

    // Scattered LDS gather (near-free).
    float xa = x_s[i1f];
    float xb = x_s[i1c];

    float vg = vv * (wf1 * xa + wc1 * xb);
    // Fixed-point integer LDS atomics (per-bank full-rate; wraparound-
    // exact two's complement).
    int ia = __float2int_rn(wf0 * vg * FP_SCALE);
    int ib = __float2int_rn(wc0 * vg * FP_SCALE);
    atomicAdd(&S_s[i0f], (unsigned int)ia);
    atomicAdd(&S_s[i0c], (unsigned int)ib);
}

__global__ __launch_bounds__(BLOCK, 8) void hyper_scatter_kernel(
    const float* __restrict__ x,    // [B, DIM]
    const float* __restrict__ ri,   // [B, N, 2]
    const float* __restrict__ rv,   // [B, N]
    float* __restrict__ partials)   // [B*SPLITS, DIM]
{
    __shared__ float        x_s[DIM];   // 32 KB staged x row (LDS gather)
    __shared__ unsigned int S_s[DIM];   // 32 KB fixed-point accumulators

    const int tid   = threadIdx.x;
    const int split = blockIdx.x;
    const int b     = blockIdx.y;

    const size_t base = (size_t)b * NPTS + (size_t)split * PTS_PER_BLOCK;
    const vf4* ri4 = (const vf4*)ri + (base >> 1);  // 2 points / 16B
    const vf2* rv2 = (const vf2*)(rv + base);

    // Prefetch pair-iter 0 BEFORE the staging barrier: these loads have no
    // LDS dependence, so their HBM latency overlaps the x4 stage loads.
    vf4 r0 = __builtin_nontemporal_load(&ri4[tid]);
    vf2 v0 = __builtin_nontemporal_load(&rv2[tid]);

    const float4* x4 = (const float4*)(x + (size_t)b * DIM);
    float4* xs4 = (float4*)x_s;
    uint4*  ss4 = (uint4*)S_s;
    #pragma unroll
    for (int i = tid; i < DIM / 4; i += BLOCK) {
        xs4[i] = x4[i];                     // L2-hit after first split per b
        ss4[i] = make_uint4(0u, 0u, 0u, 0u);
    }
    __syncthreads();

    // Iter 0 from the prefetched registers.
    process_point(r0.x, r0.y, v0.x, x_s, S_s);
    process_point(r0.z, r0.w, v0.y, x_s, S_s);

    #pragma unroll 4
    for (int k = 1; k < PITERS; ++k) {
        const int p = tid + k * BLOCK;
        vf4 r = __builtin_nontemporal_load(&ri4[p]);   // stream-once: nt
        vf2 v = __builtin_nontemporal_load(&rv2[p]);
        process_point(r.x, r.y, v.x, x_s, S_s);
        process_point(r.z, r.w, v.y, x_s, S_s);
    }
    __syncthreads();

    // Decode fixed-point -> fp32, coalesced store of the partial row.
    float* out = partials + ((size_t)b * SPLITS + split) * DIM;
    #pragma unroll
    for (int i = tid; i < DIM; i += BLOCK) {
        out[i] = (float)(int)S_s[i] * FP_INV;
    }
}

// y[b][d] = sum_s partials[b*SPLITS+s][d]; one float4 per thread.
__global__ __launch_bounds__(256) void reduce_partials_kernel(
    const float* __restrict__ partials, float* __restrict__ y)
{
    const int d4 = blockIdx.x * 256 + threadIdx.x;      // [0, B*DIM/4)
    const int b   = d4 / (DIM / 4);
    const int off = d4 % (DIM / 4);
    const float4* p = (const float4*)(partials + (size_t)b * SPLITS * DIM) + off;
    float4 acc = make_float4(0.f, 0.f, 0.f, 0.f);
    #pragma unroll
    for (int s = 0; s < SPLITS; ++s) {
        float4 v = p[(size_t)s * (DIM / 4)];
        acc.x += v.x; acc.y += v.y; acc.z += v.z; acc.w += v.w;
    }
    ((float4*)y)[d4] = acc;
}

// Fallback (ws too small): fp32 LDS accumulate + global-atomic flush.
__global__ __launch_bounds__(BLOCK, 8) void hyper_scatter_atomic_kernel(
    const float* __restrict__ x, const float* __restrict__ ri,
    const float* __restrict__ rv, float* __restrict__ y)
{
    __shared__ float x_s[DIM];
    __shared__ float y_s[DIM];
    const int tid = threadIdx.x, split = blockIdx.x, b = blockIdx.y;
    const float4* x4 = (const float4*)(x + (size_t)b * DIM);
    float4* xs4 = (float4*)x_s;
    float4* ys4 = (float4*)y_s;
    for (int i = tid; i < DIM / 4; i += BLOCK) {
        xs4[i] = x4[i];
        ys4[i] = make_float4(0.f, 0.f, 0.f, 0.f);
    }
    __syncthreads();
    const size_t base = (size_t)b * NPTS + (size_t)split * PTS_PER_BLOCK;
    const float2* idx2 = (const float2*)ri + base;
    const float*  val  = rv + base;
    for (int i = tid; i < PTS_PER_BLOCK; i += BLOCK) {
        float2 r = idx2[i];
        float v  = val[i];
        float f0 = floorf(r.x), c0 = ceilf(r.x);
        float f1 = floorf(r.y), c1 = ceilf(r.y);
        float wf0 = 1.0f - (r.x - f0), wc0 = 1.0f - (c0 - r.x);
        float wf1 = 1.0f - (r.y - f1), wc1 = 1.0f - (c1 - r.y);
        float vg = v * (wf1 * x_s[(int)f1] + wc1 * x_s[(int)c1]);
        unsafeAtomicAdd(&y_s[(int)f0], wf0 * vg);
        unsafeAtomicAdd(&y_s[(int)c0], wc0 * vg);
    }
    __syncthreads();
    float* yrow = y + (size_t)b * DIM;
    for (int i = tid; i < DIM; i += BLOCK) atomicAdd(&yrow[i], y_s[i]);
}

extern "C" void kernel_launch(void* const* d_in, const int* in_sizes, int n_in,
                              void* d_out, int out_size, void* d_ws, size_t ws_size,
                              hipStream_t stream) {
    const float* x  = (const float*)d_in[0];
    const float* ri = (const float*)d_in[1];
    const float* rv = (const float*)d_in[2];
    float* y = (float*)d_out;

    const size_t part_bytes = (size_t)BATCH * SPLITS * DIM * sizeof(float); // 8 MB
    dim3 grid(SPLITS, BATCH);

    if (ws_size >= part_bytes) {
        float* partials = (float*)d_ws;
        hyper_scatter_kernel<<<grid, BLOCK, 0, stream>>>(x, ri, rv, partials);
        const int n4 = BATCH * DIM / 4;  // 32768
        reduce_partials_kernel<<<n4 / 256, 256, 0, stream>>>(partials, y);
    } else {
        (void)hipMemsetAsync(y, 0, (size_t)out_size * sizeof(float), stream);
        hyper_scatter_atomic_kernel<<<grid, BLOCK, 0, stream>>>(x, ri, rv, y);
    }
}